// Round 8
// baseline (1018.203 us; speedup 1.0000x reference)
//
#include <hip/hip_runtime.h>
#include <math.h>

// Round 8: operand-swapped split-fp16 MFMA (compute Y^T), pair-packed LDS.
//   acc[n][m] += Wh*Xh + Wh*Xl + Wl*Xh   (A-operand = weights, B = activations)
// 256 thr / 4 waves / 128 rows per block; wave w owns rows w*32..w*32+31
// (2 row-tiles), acc[2][7]. Weight frags direct from L2 (wpk unchanged from
// round 7, now fed as the A operand -> each frag reused by 2 row-tiles:
// L2 weight traffic halves vs round 7).
// XT stores PAIR dwords {lo16 = f16(y) [RNE], hi16 = f16(y - (float)hi)}.
// C-layout of Y^T: lane holds m = lane&15 fixed, n = 16t + 4*(lane>>4) + i
// -> epilogue writes one aligned b128 per tile (was 28 scattered b32).
// No __syncthreads in the layer loop: each wave touches only its own rows.

typedef _Float16 half8 __attribute__((ext_vector_type(8)));
typedef float f32x4 __attribute__((ext_vector_type(4)));

#define TPB 256
#define RPB 128

__device__ __forceinline__ float sp100(float x) {
    // softplus(100x)/100 = max(x,0) + ln2/100 * log2(1 + 2^(-(100/ln2)*|x|))
    float t = exp2f(-144.26950408889634f * fabsf(x));
    return fmaxf(x, 0.0f) + 0.0069314718055994531f * log2f(1.0f + t);
}

// byte offset of pair-dword XT[m][k]; row stride 512 B; 16B-slot XOR swizzle
__device__ __forceinline__ int xtb(int m, int k) {
    return ((m << 9) + (k << 2)) ^ ((m & 7) << 4);
}

// split y -> packed fp16 pair: lo16 = h = f16(y), hi16 = f16(y - (float)h)
__device__ __forceinline__ unsigned int packpair(float y) {
    _Float16 h = (_Float16)y;
    float hf = (float)h;
    _Float16 l = (_Float16)(y - hf);
    union { _Float16 f; unsigned short s; } ch, cl;
    ch.f = h; cl.f = l;
    return (unsigned int)ch.s | ((unsigned int)cl.s << 16);
}

__global__ __launch_bounds__(TPB, 2) void mlp_fwd(
    const float* __restrict__ inp,
    const uint4* __restrict__ wpk,   // 7 layers x [term][s*7+t][lane] (as rnd 7)
    const float* __restrict__ W0, const float* __restrict__ b0,
    const float* __restrict__ b1, const float* __restrict__ b2,
    const float* __restrict__ b3, const float* __restrict__ b4,
    const float* __restrict__ b5, const float* __restrict__ b6,
    const float* __restrict__ b7,
    const float* __restrict__ W8, const float* __restrict__ b8,
    float* __restrict__ out)
{
    __shared__ unsigned int XT[RPB * 128];   // 64 KB pair-packed activations
    __shared__ float inps[RPB * 2];
    __shared__ float w0s[304];

    const int tid  = threadIdx.x;
    const int lane = tid & 63;
    const int wid  = tid >> 6;               // wave 0..3 -> rows wid*32..+31
    const int g    = lane >> 4;
    const int bid  = blockIdx.x;

    if (tid < RPB) {
        float2 v = *reinterpret_cast<const float2*>(inp + ((size_t)bid * RPB + tid) * 2);
        inps[tid * 2]     = v.x;
        inps[tid * 2 + 1] = v.y;
    }
    for (int q = tid; q < 304; q += TPB)
        w0s[q] = (q < 200) ? W0[q] : b0[q - 200];
    __syncthreads();   // the ONLY barrier

    // ---- L0: [2 -> 100]; wave computes its own 32 rows; zero k-pad ----
#pragma unroll
    for (int it = 0; it < 16; ++it) {
        int m = wid * 32 + it * 2 + (lane >> 5);
        int q = lane & 31;                   // col quad
        float i0 = inps[m * 2], i1 = inps[m * 2 + 1];
        unsigned int pr[4];
#pragma unroll
        for (int p = 0; p < 4; ++p) {
            int c = q * 4 + p;
            float y = 0.0f;
            if (c < 100)
                y = sp100(fmaf(i0, w0s[c * 2], fmaf(i1, w0s[c * 2 + 1], w0s[200 + c])));
            pr[p] = packpair(y);
        }
        *reinterpret_cast<uint4*>(reinterpret_cast<char*>(XT) + xtb(m, q * 4)) =
            make_uint4(pr[0], pr[1], pr[2], pr[3]);
    }

    // ---- layers 1..7, no barriers (wave-private rows) ----
#pragma unroll 1
    for (int l = 1; l <= 7; ++l) {
        const float* bp = (l == 1) ? b1 : (l == 2) ? b2 : (l == 3) ? b3 :
                          (l == 4) ? b4 : (l == 5) ? b5 : (l == 6) ? b6 : b7;
        const uint4* __restrict__ wl = wpk + (size_t)(l - 1) * 3584;

        f32x4 acc[2][7];
#pragma unroll
        for (int rt = 0; rt < 2; ++rt)
#pragma unroll
            for (int t = 0; t < 7; ++t) acc[rt][t] = f32x4{0.f, 0.f, 0.f, 0.f};

#pragma unroll
        for (int s = 0; s < 4; ++s) {
            // X fragments (B operand), both row-tiles: unpack hi/lo planes
            half8 Bh[2], Bl[2];
#pragma unroll
            for (int rt = 0; rt < 2; ++rt) {
                int m  = wid * 32 + rt * 16 + (lane & 15);
                int k0 = s * 32 + g * 8;
                uint4 pa = *reinterpret_cast<const uint4*>(
                               reinterpret_cast<const char*>(XT) + xtb(m, k0));
                uint4 pb = *reinterpret_cast<const uint4*>(
                               reinterpret_cast<const char*>(XT) + xtb(m, k0 + 4));
                union { unsigned int u[4]; half8 h; } bh, bl;
                bh.u[0] = (pa.x & 0xFFFFu) | (pa.y << 16);
                bh.u[1] = (pa.z & 0xFFFFu) | (pa.w << 16);
                bh.u[2] = (pb.x & 0xFFFFu) | (pb.y << 16);
                bh.u[3] = (pb.z & 0xFFFFu) | (pb.w << 16);
                bl.u[0] = (pa.x >> 16) | (pa.y & 0xFFFF0000u);
                bl.u[1] = (pa.z >> 16) | (pa.w & 0xFFFF0000u);
                bl.u[2] = (pb.x >> 16) | (pb.y & 0xFFFF0000u);
                bl.u[3] = (pb.z >> 16) | (pb.w & 0xFFFF0000u);
                Bh[rt] = bh.h; Bl[rt] = bl.h;
            }
#pragma unroll
            for (int t = 0; t < 7; ++t) {
                union { uint4 v; half8 h; } wh, wlo;
                wh.v  = wl[(s * 7 + t) * 64 + lane];
                wlo.v = wl[1792 + (s * 7 + t) * 64 + lane];
#pragma unroll
                for (int rt = 0; rt < 2; ++rt) {
                    acc[rt][t] = __builtin_amdgcn_mfma_f32_16x16x32_f16(wh.h,  Bh[rt], acc[rt][t], 0, 0, 0);
                    acc[rt][t] = __builtin_amdgcn_mfma_f32_16x16x32_f16(wh.h,  Bl[rt], acc[rt][t], 0, 0, 0);
                    acc[rt][t] = __builtin_amdgcn_mfma_f32_16x16x32_f16(wlo.h, Bh[rt], acc[rt][t], 0, 0, 0);
                }
            }
        }

        if (l < 7) {
            const int Nl = (l == 3) ? 98 : 100;
            const int cs = (l == 3) ? 2 : 0;
            float bv[7][4];
#pragma unroll
            for (int t = 0; t < 6; ++t) {
                float4 b4 = *reinterpret_cast<const float4*>(bp + 16 * t + 4 * g);
                bv[t][0] = b4.x; bv[t][1] = b4.y; bv[t][2] = b4.z; bv[t][3] = b4.w;
            }
#pragma unroll
            for (int i = 0; i < 4; ++i) {
                int n = 96 + 4 * g + i;
                bv[6][i] = (n < Nl) ? bp[n] : 0.0f;
            }
#pragma unroll
            for (int rt = 0; rt < 2; ++rt) {
                int m = wid * 32 + rt * 16 + (lane & 15);
#pragma unroll
                for (int t = 0; t < 7; ++t) {
                    unsigned int pr[4];
#pragma unroll
                    for (int i = 0; i < 4; ++i) {
                        int n = 16 * t + 4 * g + i;
                        float y = (n < Nl) ? sp100(acc[rt][t][i] + bv[t][i]) : 0.0f;
                        pr[i] = packpair(y);
                    }
                    int c0 = 16 * t + 4 * g + cs;
                    char* dst = reinterpret_cast<char*>(XT);
                    if (cs == 0) {
                        *reinterpret_cast<uint4*>(dst + xtb(m, c0)) =
                            make_uint4(pr[0], pr[1], pr[2], pr[3]);
                    } else {   // layer 3: col shift 2 -> two b64 writes
                        *reinterpret_cast<uint2*>(dst + xtb(m, c0))     = make_uint2(pr[0], pr[1]);
                        *reinterpret_cast<uint2*>(dst + xtb(m, c0 + 2)) = make_uint2(pr[2], pr[3]);
                    }
                }
            }
            if (l == 3 && lane < 32) {   // skip-concat: inputs -> cols 0,1 (own rows)
                int m = wid * 32 + lane;
                *reinterpret_cast<uint2*>(reinterpret_cast<char*>(XT) + xtb(m, 0)) =
                    make_uint2(packpair(inps[m * 2]), packpair(inps[m * 2 + 1]));
            }
        } else {
            // ---- fused L8: dot with W8, reduce across lane-groups ----
            float bv[7][4], w84[7][4];
#pragma unroll
            for (int t = 0; t < 6; ++t) {
                float4 b4 = *reinterpret_cast<const float4*>(bp + 16 * t + 4 * g);
                float4 w4 = *reinterpret_cast<const float4*>(W8 + 16 * t + 4 * g);
                bv[t][0] = b4.x; bv[t][1] = b4.y; bv[t][2] = b4.z; bv[t][3] = b4.w;
                w84[t][0] = w4.x; w84[t][1] = w4.y; w84[t][2] = w4.z; w84[t][3] = w4.w;
            }
#pragma unroll
            for (int i = 0; i < 4; ++i) {
                int n = 96 + 4 * g + i;
                bv[6][i]  = (n < 100) ? bp[n] : 0.0f;
                w84[6][i] = (n < 100) ? W8[n] : 0.0f;   // pad-n weight 0 -> safe
            }
            float p8[2] = {0.0f, 0.0f};
#pragma unroll
            for (int rt = 0; rt < 2; ++rt)
#pragma unroll
                for (int t = 0; t < 7; ++t)
#pragma unroll
                    for (int i = 0; i < 4; ++i)
                        p8[rt] = fmaf(w84[t][i], sp100(acc[rt][t][i] + bv[t][i]), p8[rt]);
            float b8v = b8[0];
#pragma unroll
            for (int rt = 0; rt < 2; ++rt) {
                float v = p8[rt];
                v += __shfl_xor(v, 16);
                v += __shfl_xor(v, 32);
                if (lane < 16)
                    out[(size_t)bid * RPB + wid * 32 + rt * 16 + lane] = v + b8v;
            }
        }
    }
}

// Pack W1..W7 ([out][in=100] fp32) -> per-layer [term(h/l)][s*7+t][lane] half8:
// half jj at k=32s+8*(lane>>4)+jj, n=16t+(lane&15);
// term0=(f16)W, term1=(f16)(W-(float)(f16)W). Zero outside K=100 / N=Nl.
// (Unchanged from round 7; now consumed as the MFMA *A* operand.)
__global__ void pack_weights(
    const float* __restrict__ W1, const float* __restrict__ W2,
    const float* __restrict__ W3, const float* __restrict__ W4,
    const float* __restrict__ W5, const float* __restrict__ W6,
    const float* __restrict__ W7, uint4* __restrict__ wpk)
{
    const float* Wt[7] = {W1, W2, W3, W4, W5, W6, W7};
    const float* W = Wt[blockIdx.x];
    const int Nl = (blockIdx.x == 2) ? 98 : 100;   // layer 3 outputs 98
    for (int e = threadIdx.x; e < 3584; e += 256) {
        int term = e / 1792;
        int r    = e - term * 1792;
        int lane = r & 63;
        int st   = r >> 6;
        int s    = st / 7;
        int t    = st - s * 7;
        union { _Float16 h[8]; uint4 v; } pk;
#pragma unroll
        for (int jj = 0; jj < 8; ++jj) {
            int k = s * 32 + (lane >> 4) * 8 + jj;
            int n = t * 16 + (lane & 15);
            float val = (k < 100 && n < Nl) ? W[n * 100 + k] : 0.0f;
            _Float16 h = (_Float16)val;
            pk.h[jj] = term ? (_Float16)(val - (float)h) : h;
        }
        wpk[blockIdx.x * 3584 + term * 1792 + r] = pk.v;
    }
}

extern "C" void kernel_launch(void* const* d_in, const int* in_sizes, int n_in,
                              void* d_out, int out_size, void* d_ws, size_t ws_size,
                              hipStream_t stream)
{
    const float* inp = (const float*)d_in[0];
    const float* W[9];
    const float* B[9];
    for (int l = 0; l < 9; ++l) {
        W[l] = (const float*)d_in[1 + 2 * l];
        B[l] = (const float*)d_in[2 + 2 * l];
    }
    uint4* wpk = (uint4*)d_ws;             // 7*3584*16 = 401,408 B
    float* out = (float*)d_out;
    const int N = in_sizes[0] / 2;         // 1,048,576 rows

    pack_weights<<<7, 256, 0, stream>>>(W[1], W[2], W[3], W[4], W[5], W[6], W[7], wpk);
    mlp_fwd<<<N / RPB, TPB, 0, stream>>>(inp, wpk,
                                         W[0], B[0],
                                         B[1], B[2], B[3], B[4], B[5], B[6], B[7],
                                         W[8], B[8],
                                         out);
}

// Round 9
// 769.355 us; speedup vs baseline: 1.3234x; 1.3234x over previous
//
#include <hip/hip_runtime.h>
#include <math.h>

// Round 9: rnd-8 structure + (1) HW transcendentals (v_exp_f32/v_log_f32 via
// builtins -- plain -O3 lowers exp2f/log2f to slow libm-safe sequences, which
// was ~600us of hidden VALU in rounds 1-8), (2) bias folded into weights at
// k=100 with X col 100 == 1.0, (3) plane-separated hi/lo fp16 LDS (no bitops,
// aligned b64/b128 plane accesses).
// 256 thr / 4 waves / 128 rows; wave owns 32 rows (rt=2), acc[2][7].
// Weights (A operand) direct from L2, reused across 2 row-tiles.

typedef _Float16 half8 __attribute__((ext_vector_type(8)));
typedef _Float16 half4v __attribute__((ext_vector_type(4)));
typedef float f32x4 __attribute__((ext_vector_type(4)));

#define TPB 256
#define RPB 128

__device__ __forceinline__ float sp100(float x) {
    // softplus(100x)/100 = max(x,0) + ln2/100 * log2(1 + 2^(-(100/ln2)*|x|))
    float t = __builtin_amdgcn_exp2f(-144.26950408889634f * fabsf(x));
    return fmaxf(x, 0.0f) + 0.0069314718055994531f * __builtin_amdgcn_logf(1.0f + t);
}

// byte offset into an fp16 plane [128 rows][128 k]; row stride 256 B;
// 16B-granule XOR swizzle
__device__ __forceinline__ int xhb(int m, int k) {
    return ((m << 8) + (k << 1)) ^ ((m & 7) << 4);
}

__global__ __launch_bounds__(TPB, 2) void mlp_fwd(
    const float* __restrict__ inp,
    const uint4* __restrict__ wpk,   // 7 layers x [term][s*7+t][lane], bias at k=100
    const float* __restrict__ W0, const float* __restrict__ b0,
    const float* __restrict__ W8, const float* __restrict__ b8,
    float* __restrict__ out)
{
    __shared__ _Float16 XH[RPB * 128];   // 32 KB hi plane
    __shared__ _Float16 XL[RPB * 128];   // 32 KB lo plane
    __shared__ float inps[RPB * 2];
    __shared__ float w0s[304];

    const int tid  = threadIdx.x;
    const int lane = tid & 63;
    const int wid  = tid >> 6;           // wave 0..3 -> rows wid*32..+31
    const int g    = lane >> 4;
    const int bid  = blockIdx.x;

    if (tid < RPB) {
        float2 v = *reinterpret_cast<const float2*>(inp + ((size_t)bid * RPB + tid) * 2);
        inps[tid * 2]     = v.x;
        inps[tid * 2 + 1] = v.y;
    }
    for (int q = tid; q < 304; q += TPB)
        w0s[q] = (q < 200) ? W0[q] : b0[q - 200];
    __syncthreads();   // the only barrier

    // ---- L0: [2 -> 100]; wave fills its own 32 rows; col 100 = 1.0; pad 0 ----
#pragma unroll
    for (int it = 0; it < 16; ++it) {
        int m = wid * 32 + it * 2 + (lane >> 5);
        int q = lane & 31;               // col quad: cols 4q..4q+3
        float i0 = inps[m * 2], i1 = inps[m * 2 + 1];
        half4v hh, hl;
#pragma unroll
        for (int p = 0; p < 4; ++p) {
            int c = q * 4 + p;
            float y = (c < 100)
                ? sp100(fmaf(i0, w0s[c * 2], fmaf(i1, w0s[c * 2 + 1], w0s[200 + c])))
                : ((c == 100) ? 1.0f : 0.0f);
            _Float16 h = (_Float16)y;
            hh[p] = h;
            hl[p] = (_Float16)(y - (float)h);
        }
        *reinterpret_cast<half4v*>(reinterpret_cast<char*>(XH) + xhb(m, q * 4)) = hh;
        *reinterpret_cast<half4v*>(reinterpret_cast<char*>(XL) + xhb(m, q * 4)) = hl;
    }

    // ---- layers 1..7, no barriers (wave-private rows) ----
#pragma unroll 1
    for (int l = 1; l <= 7; ++l) {
        const uint4* __restrict__ wl = wpk + (size_t)(l - 1) * 3584;

        f32x4 acc[2][7];
#pragma unroll
        for (int rt = 0; rt < 2; ++rt)
#pragma unroll
            for (int t = 0; t < 7; ++t) acc[rt][t] = f32x4{0.f, 0.f, 0.f, 0.f};

#pragma unroll
        for (int s = 0; s < 4; ++s) {
            half8 Bh[2], Bl[2];
#pragma unroll
            for (int rt = 0; rt < 2; ++rt) {
                int m  = wid * 32 + rt * 16 + (lane & 15);
                int k0 = s * 32 + g * 8;
                Bh[rt] = *reinterpret_cast<const half8*>(
                             reinterpret_cast<const char*>(XH) + xhb(m, k0));
                Bl[rt] = *reinterpret_cast<const half8*>(
                             reinterpret_cast<const char*>(XL) + xhb(m, k0));
            }
#pragma unroll
            for (int t = 0; t < 7; ++t) {
                union { uint4 v; half8 h; } wh, wlo;
                wh.v  = wl[(s * 7 + t) * 64 + lane];
                wlo.v = wl[1792 + (s * 7 + t) * 64 + lane];
#pragma unroll
                for (int rt = 0; rt < 2; ++rt) {
                    acc[rt][t] = __builtin_amdgcn_mfma_f32_16x16x32_f16(wh.h,  Bh[rt], acc[rt][t], 0, 0, 0);
                    acc[rt][t] = __builtin_amdgcn_mfma_f32_16x16x32_f16(wh.h,  Bl[rt], acc[rt][t], 0, 0, 0);
                    acc[rt][t] = __builtin_amdgcn_mfma_f32_16x16x32_f16(wlo.h, Bh[rt], acc[rt][t], 0, 0, 0);
                }
            }
        }

        if (l < 7) {
            const int Nl = (l == 3) ? 98 : 100;
#pragma unroll
            for (int rt = 0; rt < 2; ++rt) {
                int m = wid * 32 + rt * 16 + (lane & 15);
#pragma unroll
                for (int t = 0; t < 7; ++t) {
                    half4v hh, hl;
#pragma unroll
                    for (int i = 0; i < 4; ++i) {
                        int n = 16 * t + 4 * g + i;
                        float y = (n < Nl) ? sp100(acc[rt][t][i])
                                           : ((n == Nl) ? 1.0f : 0.0f);
                        _Float16 h = (_Float16)y;
                        hh[i] = h;
                        hl[i] = (_Float16)(y - (float)h);
                    }
                    if (l != 3) {
                        *reinterpret_cast<half4v*>(
                            reinterpret_cast<char*>(XH) + xhb(m, 16 * t + 4 * g)) = hh;
                        *reinterpret_cast<half4v*>(
                            reinterpret_cast<char*>(XL) + xhb(m, 16 * t + 4 * g)) = hl;
                    } else {   // col shift +2: scalar b16 (granule-crossing b64)
#pragma unroll
                        for (int i = 0; i < 4; ++i) {
                            int c = 16 * t + 4 * g + i + 2;
                            *reinterpret_cast<_Float16*>(
                                reinterpret_cast<char*>(XH) + xhb(m, c)) = hh[i];
                            *reinterpret_cast<_Float16*>(
                                reinterpret_cast<char*>(XL) + xhb(m, c)) = hl[i];
                        }
                    }
                }
            }
            if (l == 3 && lane < 32) {   // skip-concat: inputs -> cols 0,1
                int m = wid * 32 + lane;
#pragma unroll
                for (int c = 0; c < 2; ++c) {
                    float v = inps[m * 2 + c];
                    _Float16 h = (_Float16)v;
                    *reinterpret_cast<_Float16*>(
                        reinterpret_cast<char*>(XH) + xhb(m, c)) = h;
                    *reinterpret_cast<_Float16*>(
                        reinterpret_cast<char*>(XL) + xhb(m, c)) = (_Float16)(v - (float)h);
                }
            }
        } else {
            // ---- fused L8: dot with W8 (b7 already inside acc), reduce ----
            float w84[7][4];
#pragma unroll
            for (int t = 0; t < 6; ++t) {
                float4 w4 = *reinterpret_cast<const float4*>(W8 + 16 * t + 4 * g);
                w84[t][0] = w4.x; w84[t][1] = w4.y; w84[t][2] = w4.z; w84[t][3] = w4.w;
            }
#pragma unroll
            for (int i = 0; i < 4; ++i) {
                int n = 96 + 4 * g + i;
                w84[6][i] = (n < 100) ? W8[n] : 0.0f;
            }
            float p8[2] = {0.0f, 0.0f};
#pragma unroll
            for (int rt = 0; rt < 2; ++rt)
#pragma unroll
                for (int t = 0; t < 7; ++t)
#pragma unroll
                    for (int i = 0; i < 4; ++i)
                        p8[rt] = fmaf(w84[t][i], sp100(acc[rt][t][i]), p8[rt]);
            float b8v = b8[0];
#pragma unroll
            for (int rt = 0; rt < 2; ++rt) {
                float v = p8[rt];
                v += __shfl_xor(v, 16);
                v += __shfl_xor(v, 32);
                if (lane < 16)
                    out[(size_t)bid * RPB + wid * 32 + rt * 16 + lane] = v + b8v;
            }
        }
    }
}

// Pack W1..W7 (+ biases b1..b7 at k=100) -> per-layer [term][s*7+t][lane] half8:
// half jj at k=32s+8*(lane>>4)+jj, n=16t+(lane&15);
//   k<100: W[n][k];  k==100: b[n];  else 0.  (zero outside n<Nl)
// term0=(f16)val, term1=(f16)(val-(float)(f16)val).
__global__ void pack_weights(
    const float* __restrict__ W1, const float* __restrict__ W2,
    const float* __restrict__ W3, const float* __restrict__ W4,
    const float* __restrict__ W5, const float* __restrict__ W6,
    const float* __restrict__ W7,
    const float* __restrict__ b1, const float* __restrict__ b2,
    const float* __restrict__ b3, const float* __restrict__ b4,
    const float* __restrict__ b5, const float* __restrict__ b6,
    const float* __restrict__ b7,
    uint4* __restrict__ wpk)
{
    const float* Wt[7] = {W1, W2, W3, W4, W5, W6, W7};
    const float* Bt[7] = {b1, b2, b3, b4, b5, b6, b7};
    const float* W = Wt[blockIdx.x];
    const float* B = Bt[blockIdx.x];
    const int Nl = (blockIdx.x == 2) ? 98 : 100;   // layer 3 outputs 98
    for (int e = threadIdx.x; e < 3584; e += 256) {
        int term = e / 1792;
        int r    = e - term * 1792;
        int lane = r & 63;
        int st   = r >> 6;
        int s    = st / 7;
        int t    = st - s * 7;
        union { _Float16 h[8]; uint4 v; } pk;
#pragma unroll
        for (int jj = 0; jj < 8; ++jj) {
            int k = s * 32 + (lane >> 4) * 8 + jj;
            int n = t * 16 + (lane & 15);
            float val = 0.0f;
            if (n < Nl) {
                if (k < 100)       val = W[n * 100 + k];
                else if (k == 100) val = B[n];
            }
            _Float16 h = (_Float16)val;
            pk.h[jj] = term ? (_Float16)(val - (float)h) : h;
        }
        wpk[blockIdx.x * 3584 + term * 1792 + r] = pk.v;
    }
}

extern "C" void kernel_launch(void* const* d_in, const int* in_sizes, int n_in,
                              void* d_out, int out_size, void* d_ws, size_t ws_size,
                              hipStream_t stream)
{
    const float* inp = (const float*)d_in[0];
    const float* W[9];
    const float* B[9];
    for (int l = 0; l < 9; ++l) {
        W[l] = (const float*)d_in[1 + 2 * l];
        B[l] = (const float*)d_in[2 + 2 * l];
    }
    uint4* wpk = (uint4*)d_ws;             // 7*3584*16 = 401,408 B
    float* out = (float*)d_out;
    const int N = in_sizes[0] / 2;         // 1,048,576 rows

    pack_weights<<<7, 256, 0, stream>>>(W[1], W[2], W[3], W[4], W[5], W[6], W[7],
                                        B[1], B[2], B[3], B[4], B[5], B[6], B[7],
                                        wpk);
    mlp_fwd<<<N / RPB, TPB, 0, stream>>>(inp, wpk,
                                         W[0], B[0], W[8], B[8],
                                         out);
}